// Round 8
// baseline (45.707 us; speedup 1.0000x reference)
//
#include <hip/hip_runtime.h>

#define NP 16384
#define NS 8192
#define DP 256
#define DS 128
#define DI 128

// ---- k1 geometry: byte-balanced static split, 256 blocks exactly ----
#define NBP 205               // prot blocks: 80 rows each (last 64)
#define NBS 51                // sub blocks: 160 rows each (last 192)
#define G1  (NBP + NBS)       // 256
#define PROWS 80
#define SROWS 160

// ---- ws float offsets ----
#define RP_OFF 0                      // [NBP][DS] projected prot partials (-> u_s)
#define RS_OFF (RP_OFF + NBP*DS)      // [NBS][DP] projected sub partials (-> u_p)
#define ZP_OFF (RS_OFF + NBS*DP)      // [NBP]
#define ZS_OFF (ZP_OFF + NBP)         // [NBS]
#define BSC    (ZS_OFF + NBS)         // [DS] bso + Wso^T bpp
#define BPC    (BSC + DS)             // [DP] bpo + Wpo^T bsp

// ---- out float offsets ----
#define O1 (NP*DP)
#define O2 (O1 + NP)
#define O3 (O2 + NS*DS)
#define TOTAL (O3 + NS)
#define TOTAL4 (TOTAL/4)     // 1316864
#define G2  1024
#define CH4 (TOTAL4 / G2)    // 1286 exactly

// ---- k1: balanced fused gather-weight + weighted colsum + per-block projection ----
__global__ __launch_bounds__(512)
void k1(const float* __restrict__ pn, const float* __restrict__ sn,
        const float* __restrict__ Wpp, const float* __restrict__ bpp,
        const float* __restrict__ Wsp, const float* __restrict__ bsp,
        const float* __restrict__ Wpo, const float* __restrict__ bpo,
        const float* __restrict__ Wso, const float* __restrict__ bso,
        const int* __restrict__ pidx, const int* __restrict__ sidx,
        float* __restrict__ ws) {
    __shared__ float wcol[DP];
    __shared__ float racc[8 * DP];
    __shared__ float rz[8];
    __shared__ float acc2[DP];
    __shared__ float qv[DI];
    __shared__ float red[512];
    const int t = threadIdx.x;
    const int lane = t & 63;
    const int wv = t >> 6;
    const int b = blockIdx.x;

    if (b < NBP) {
        // ---- prot side: rows [b*80, b*80+80) (last block 64) ----
        if (t < DP) {
            const float4* row = (const float4*)(Wpp + t * DI);
            float s = 0.f;
            #pragma unroll
            for (int d = 0; d < DI / 4; ++d) { float4 v = row[d]; s += v.x + v.y + v.z + v.w; }
            wcol[t] = s;
        }
        __syncthreads();
        const float4 wp = *(const float4*)(wcol + lane * 4);
        float4 acc = make_float4(0.f, 0.f, 0.f, 0.f);
        float z = 0.f;
        const int rowStart = b * PROWS;
        const int rowEnd = (b == NBP - 1) ? NP : rowStart + PROWS;
        for (int row = rowStart + wv * 2; row < rowEnd; row += 16) {
            const int i0 = row, i1 = row + 1;
            const int g0 = pidx[i0], g1 = pidx[i1];
            const float4 x0 = *(const float4*)(pn + (size_t)g0 * DP + lane * 4);
            const float4 x1 = *(const float4*)(pn + (size_t)g1 * DP + lane * 4);
            float s0 = x0.x * wp.x + x0.y * wp.y + x0.z * wp.z + x0.w * wp.w;
            float s1 = x1.x * wp.x + x1.y * wp.y + x1.z * wp.z + x1.w * wp.w;
            #pragma unroll
            for (int m = 32; m >= 1; m >>= 1) {
                s0 += __shfl_xor(s0, m, 64);
                s1 += __shfl_xor(s1, m, 64);
            }
            const float e0 = __expf(s0), e1 = __expf(s1);
            const float4 y0 = *(const float4*)(pn + (size_t)i0 * DP + lane * 4);
            const float4 y1 = *(const float4*)(pn + (size_t)i1 * DP + lane * 4);
            acc.x += e0 * y0.x + e1 * y1.x;
            acc.y += e0 * y0.y + e1 * y1.y;
            acc.z += e0 * y0.z + e1 * y1.z;
            acc.w += e0 * y0.w + e1 * y1.w;
            z += e0 + e1;
        }
        ((float4*)(racc + wv * DP))[lane] = acc;
        if (lane == 0) rz[wv] = z;
        __syncthreads();
        if (t < DP) {
            float s = 0.f;
            #pragma unroll
            for (int w = 0; w < 8; ++w) s += racc[w * DP + t];
            acc2[t] = s;
        }
        if (t == 0) {
            float s = 0.f;
            #pragma unroll
            for (int w = 0; w < 8; ++w) s += rz[w];
            ws[ZP_OFF + b] = s;
        }
        __syncthreads();
        // stage A: q[d] = sum_c acc2[c]*Wpp[c][d]
        {
            const int d = t & 127, g = t >> 7;
            float a = 0.f;
            #pragma unroll 8
            for (int c = g * 64; c < g * 64 + 64; ++c) a += acc2[c] * Wpp[c * DI + d];
            red[t] = a;
        }
        __syncthreads();
        if (t < DI) qv[t] = red[t] + red[t + 128] + red[t + 256] + red[t + 384];
        __syncthreads();
        // stage B: r[c] = sum_d qv[d]*Wso[d][c]
        {
            const int c = t & 127, g = t >> 7;
            float a = 0.f;
            #pragma unroll 8
            for (int d = g * 32; d < g * 32 + 32; ++d) a += qv[d] * Wso[d * DS + c];
            red[t] = a;
        }
        __syncthreads();
        if (t < DS) ws[RP_OFF + b * DS + t] = red[t] + red[t + 128] + red[t + 256] + red[t + 384];
        if (b == 0) {  // BSC = bso + Wso^T bpp
            __syncthreads();
            {
                const int c = t & 127, g = t >> 7;
                float a = 0.f;
                #pragma unroll 8
                for (int d = g * 32; d < g * 32 + 32; ++d) a += bpp[d] * Wso[d * DS + c];
                red[t] = a;
            }
            __syncthreads();
            if (t < DS) ws[BSC + t] = bso[t] + red[t] + red[t + 128] + red[t + 256] + red[t + 384];
        }
    } else {
        // ---- sub side: rows [b2*160, +160) (last block 192) ----
        const int b2 = b - NBP;
        if (t < DS) {
            const float4* row = (const float4*)(Wsp + t * DI);
            float s = 0.f;
            #pragma unroll
            for (int d = 0; d < DI / 4; ++d) { float4 v = row[d]; s += v.x + v.y + v.z + v.w; }
            wcol[t] = s;
        }
        __syncthreads();
        const float2 wp = *(const float2*)(wcol + lane * 2);
        float2 acc = make_float2(0.f, 0.f);
        float z = 0.f;
        const int rowStart = b2 * SROWS;
        const int rowEnd = (b2 == NBS - 1) ? NS : rowStart + SROWS;
        for (int row = rowStart + wv * 2; row < rowEnd; row += 16) {
            const int j0 = row, j1 = row + 1;
            const int g0 = sidx[j0], g1 = sidx[j1];
            const float2 x0 = *(const float2*)(sn + (size_t)g0 * DS + lane * 2);
            const float2 x1 = *(const float2*)(sn + (size_t)g1 * DS + lane * 2);
            float s0 = x0.x * wp.x + x0.y * wp.y;
            float s1 = x1.x * wp.x + x1.y * wp.y;
            #pragma unroll
            for (int m = 32; m >= 1; m >>= 1) {
                s0 += __shfl_xor(s0, m, 64);
                s1 += __shfl_xor(s1, m, 64);
            }
            const float e0 = __expf(s0), e1 = __expf(s1);
            const float2 y0 = *(const float2*)(sn + (size_t)j0 * DS + lane * 2);
            const float2 y1 = *(const float2*)(sn + (size_t)j1 * DS + lane * 2);
            acc.x += e0 * y0.x + e1 * y1.x;
            acc.y += e0 * y0.y + e1 * y1.y;
            z += e0 + e1;
        }
        ((float2*)(racc + wv * DS))[lane] = acc;
        if (lane == 0) rz[wv] = z;
        __syncthreads();
        if (t < DS) {
            float s = 0.f;
            #pragma unroll
            for (int w = 0; w < 8; ++w) s += racc[w * DS + t];
            acc2[t] = s;
        }
        if (t == 0) {
            float s = 0.f;
            #pragma unroll
            for (int w = 0; w < 8; ++w) s += rz[w];
            ws[ZS_OFF + b2] = s;
        }
        __syncthreads();
        // stage A: q[d] = sum_c acc2[c]*Wsp[c][d]
        {
            const int d = t & 127, g = t >> 7;
            float a = 0.f;
            #pragma unroll 8
            for (int c = g * 32; c < g * 32 + 32; ++c) a += acc2[c] * Wsp[c * DI + d];
            red[t] = a;
        }
        __syncthreads();
        if (t < DI) qv[t] = red[t] + red[t + 128] + red[t + 256] + red[t + 384];
        __syncthreads();
        // stage B: r[c] = sum_d qv[d]*Wpo[d][c]
        {
            const int c = t & 255, g = t >> 8;
            float a = 0.f;
            #pragma unroll 8
            for (int d = g * 64; d < g * 64 + 64; ++d) a += qv[d] * Wpo[d * DP + c];
            red[t] = a;
        }
        __syncthreads();
        if (t < DP) ws[RS_OFF + b2 * DP + t] = red[t] + red[t + 256];
        if (b2 == 0) {  // BPC = bpo + Wpo^T bsp
            __syncthreads();
            {
                const int c = t & 255, g = t >> 8;
                float a = 0.f;
                #pragma unroll 8
                for (int d = g * 64; d < g * 64 + 64; ++d) a += bsp[d] * Wpo[d * DP + c];
                red[t] = a;
            }
            __syncthreads();
            if (t < DP) ws[BPC + t] = bpo[t] + red[t] + red[t + 256];
        }
    }
}

// ---- k2: R6 structure — combine first, then stream (no preload) ----
__global__ __launch_bounds__(512)
void k2(const float* __restrict__ pn, const float* __restrict__ sn,
        const int* __restrict__ pidx, const int* __restrict__ sidx,
        const float* __restrict__ ws, float* __restrict__ out) {
    __shared__ float up[DP];
    __shared__ float us[DS];
    __shared__ float red[512];
    __shared__ float zsh[2];
    const int t = threadIdx.x;
    const int lane = t & 63;
    const int wv = t >> 6;
    const int b = blockIdx.x;
    const int start4 = b * CH4;
    const int end4 = start4 + CH4;

    if (wv == 0) {
        float z = ws[ZP_OFF + lane] + ws[ZP_OFF + 64 + lane] + ws[ZP_OFF + 128 + lane]
                + ((lane < NBP - 192) ? ws[ZP_OFF + 192 + lane] : 0.f);
        #pragma unroll
        for (int m = 32; m >= 1; m >>= 1) z += __shfl_xor(z, m, 64);
        if (lane == 0) zsh[0] = z;
    } else if (wv == 1) {
        float z = (lane < NBS) ? ws[ZS_OFF + lane] : 0.f;
        #pragma unroll
        for (int m = 32; m >= 1; m >>= 1) z += __shfl_xor(z, m, 64);
        if (lane == 0) zsh[1] = z;
    }
    __syncthreads();
    const float invZp = 1.f / zsh[0];
    const float invZs = 1.f / zsh[1];

    const bool needP = start4 < (O1 / 4);
    const bool needS = (end4 > (O2 / 4)) && (start4 < (O3 / 4));

    if (needP) {   // u_p = BPC + invZs * sum_b2 RS[b2][:]
        {
            const int c = t & 255, g = t >> 8;         // 2 groups of <=26 blocks
            const int beg = g * 26, fin = (g == 0) ? 26 : NBS;
            float a = 0.f;
            for (int b2 = beg; b2 < fin; ++b2) a += ws[RS_OFF + b2 * DP + c];
            red[t] = a;
        }
        __syncthreads();
        if (t < DP) up[t] = ws[BPC + t] + invZs * (red[t] + red[t + 256]);
        __syncthreads();
    }
    if (needS) {   // u_s = BSC + invZp * sum_b1 RP[b1][:]
        {
            const int c = t & 127, g = t >> 7;         // 4 groups of <=52 blocks
            const int beg = g * 52, fin = (g == 3) ? NBP : beg + 52;
            float a = 0.f;
            for (int b1 = beg; b1 < fin; ++b1) a += ws[RP_OFF + b1 * DS + c];
            red[t] = a;
        }
        __syncthreads();
        if (t < DS) us[t] = ws[BSC + t] + invZp * (red[t] + red[t + 128] + red[t + 256] + red[t + 384]);
        __syncthreads();
    }

    for (int g4 = start4 + t; g4 < end4; g4 += 512) {
        const int e4 = g4 * 4;
        float4 o;
        if (e4 < O1) {
            float4 x = *(const float4*)(pn + e4);
            int c = e4 & (DP - 1);
            o = make_float4(x.x + up[c], x.y + up[c + 1], x.z + up[c + 2], x.w + up[c + 3]);
        } else if (e4 < O2) {
            int i = e4 - O1;
            int4 v = *(const int4*)(pidx + i);
            o = make_float4((float)v.x, (float)v.y, (float)v.z, (float)v.w);
        } else if (e4 < O3) {
            int i = e4 - O2;
            float4 x = *(const float4*)(sn + i);
            int c = i & (DS - 1);
            o = make_float4(x.x + us[c], x.y + us[c + 1], x.z + us[c + 2], x.w + us[c + 3]);
        } else {
            int i = e4 - O3;
            int4 v = *(const int4*)(sidx + i);
            o = make_float4((float)v.x, (float)v.y, (float)v.z, (float)v.w);
        }
        *(float4*)(out + e4) = o;
    }
}

extern "C" void kernel_launch(void* const* d_in, const int* in_sizes, int n_in,
                              void* d_out, int out_size, void* d_ws, size_t ws_size,
                              hipStream_t stream) {
    const float* pn  = (const float*)d_in[0];
    const float* sn  = (const float*)d_in[1];
    const float* Wpp = (const float*)d_in[2];
    const float* bpp = (const float*)d_in[3];
    const float* Wsp = (const float*)d_in[4];
    const float* bsp = (const float*)d_in[5];
    const float* Wpo = (const float*)d_in[6];
    const float* bpo = (const float*)d_in[7];
    const float* Wso = (const float*)d_in[8];
    const float* bso = (const float*)d_in[9];
    const int* pidx  = (const int*)d_in[10];
    const int* sidx  = (const int*)d_in[11];
    float* ws  = (float*)d_ws;
    float* out = (float*)d_out;

    hipLaunchKernelGGL(k1, dim3(G1), dim3(512), 0, stream,
                       pn, sn, Wpp, bpp, Wsp, bsp, Wpo, bpo, Wso, bso, pidx, sidx, ws);
    hipLaunchKernelGGL(k2, dim3(G2), dim3(512), 0, stream,
                       pn, sn, pidx, sidx, ws, out);
}

// Round 9
// 35.745 us; speedup vs baseline: 1.2787x; 1.2787x over previous
//
#include <hip/hip_runtime.h>

#define NP 16384
#define NS 8192
#define DP 256
#define DS 128
#define DI 128

// ---- k1 geometry: constant trip counts (fully unrollable) ----
#define NBP 256               // prot blocks: 64 rows each (8 rows/wave)
#define NBS 64                // sub blocks: 128 rows each (16 rows/wave)
#define G1  (NBP + NBS)       // 320

// ---- ws float offsets ----
#define RP_OFF 0                      // [NBP][DS] projected prot partials (-> u_s)
#define RS_OFF (RP_OFF + NBP*DS)      // [NBS][DP] projected sub partials (-> u_p)
#define ZP_OFF (RS_OFF + NBS*DP)      // [NBP]
#define ZS_OFF (ZP_OFF + NBP)         // [NBS]
#define BSC    (ZS_OFF + NBS)         // [DS] bso + Wso^T bpp
#define BPC    (BSC + DS)             // [DP] bpo + Wpo^T bsp

// ---- out float offsets ----
#define O1 (NP*DP)
#define O2 (O1 + NP)
#define O3 (O2 + NS*DS)
#define TOTAL (O3 + NS)
#define TOTAL4 (TOTAL/4)     // 1316864
#define G2  512
#define CH4 (TOTAL4 / G2)    // 2572 exactly

// ---- k1: fused gather-weight + weighted colsum + per-block projection ----
__global__ __launch_bounds__(512)
void k1(const float* __restrict__ pn, const float* __restrict__ sn,
        const float* __restrict__ Wpp, const float* __restrict__ bpp,
        const float* __restrict__ Wsp, const float* __restrict__ bsp,
        const float* __restrict__ Wpo, const float* __restrict__ bpo,
        const float* __restrict__ Wso, const float* __restrict__ bso,
        const int* __restrict__ pidx, const int* __restrict__ sidx,
        float* __restrict__ ws) {
    __shared__ float wcol[DP];
    __shared__ float racc[8 * DP];
    __shared__ float rz[8];
    __shared__ float acc2[DP];
    __shared__ float qv[DI];
    __shared__ float red[512];
    const int t = threadIdx.x;
    const int lane = t & 63;
    const int wv = t >> 6;
    const int b = blockIdx.x;

    if (b < NBP) {
        // ---- prot side: 64 rows, 8 per wave, FULLY UNROLLED ----
        if (t < DP) {
            const float4* row = (const float4*)(Wpp + t * DI);
            float s = 0.f;
            #pragma unroll
            for (int d = 0; d < DI / 4; ++d) { float4 v = row[d]; s += v.x + v.y + v.z + v.w; }
            wcol[t] = s;
        }
        __syncthreads();
        const float4 wp = *(const float4*)(wcol + lane * 4);
        float4 acc = make_float4(0.f, 0.f, 0.f, 0.f);
        float z = 0.f;
        const int base = (b * 8 + wv) * 8;          // 8 rows per wave
        #pragma unroll
        for (int k = 0; k < 8; k += 2) {
            const int i0 = base + k, i1 = base + k + 1;
            const int g0 = pidx[i0], g1 = pidx[i1];
            const float4 x0 = *(const float4*)(pn + (size_t)g0 * DP + lane * 4);
            const float4 x1 = *(const float4*)(pn + (size_t)g1 * DP + lane * 4);
            float s0 = x0.x * wp.x + x0.y * wp.y + x0.z * wp.z + x0.w * wp.w;
            float s1 = x1.x * wp.x + x1.y * wp.y + x1.z * wp.z + x1.w * wp.w;
            #pragma unroll
            for (int m = 32; m >= 1; m >>= 1) {
                s0 += __shfl_xor(s0, m, 64);
                s1 += __shfl_xor(s1, m, 64);
            }
            const float e0 = __expf(s0), e1 = __expf(s1);
            const float4 y0 = *(const float4*)(pn + (size_t)i0 * DP + lane * 4);
            const float4 y1 = *(const float4*)(pn + (size_t)i1 * DP + lane * 4);
            acc.x += e0 * y0.x + e1 * y1.x;
            acc.y += e0 * y0.y + e1 * y1.y;
            acc.z += e0 * y0.z + e1 * y1.z;
            acc.w += e0 * y0.w + e1 * y1.w;
            z += e0 + e1;
        }
        ((float4*)(racc + wv * DP))[lane] = acc;
        if (lane == 0) rz[wv] = z;
        __syncthreads();
        if (t < DP) {
            float s = 0.f;
            #pragma unroll
            for (int w = 0; w < 8; ++w) s += racc[w * DP + t];
            acc2[t] = s;
        }
        if (t == 0) {
            float s = 0.f;
            #pragma unroll
            for (int w = 0; w < 8; ++w) s += rz[w];
            ws[ZP_OFF + b] = s;
        }
        __syncthreads();
        // stage A: q[d] = sum_c acc2[c]*Wpp[c][d]
        {
            const int d = t & 127, g = t >> 7;
            float a = 0.f;
            #pragma unroll 8
            for (int c = g * 64; c < g * 64 + 64; ++c) a += acc2[c] * Wpp[c * DI + d];
            red[t] = a;
        }
        __syncthreads();
        if (t < DI) qv[t] = red[t] + red[t + 128] + red[t + 256] + red[t + 384];
        __syncthreads();
        // stage B: r[c] = sum_d qv[d]*Wso[d][c]
        {
            const int c = t & 127, g = t >> 7;
            float a = 0.f;
            #pragma unroll 8
            for (int d = g * 32; d < g * 32 + 32; ++d) a += qv[d] * Wso[d * DS + c];
            red[t] = a;
        }
        __syncthreads();
        if (t < DS) ws[RP_OFF + b * DS + t] = red[t] + red[t + 128] + red[t + 256] + red[t + 384];
        if (b == 0) {  // BSC = bso + Wso^T bpp
            __syncthreads();
            {
                const int c = t & 127, g = t >> 7;
                float a = 0.f;
                #pragma unroll 8
                for (int d = g * 32; d < g * 32 + 32; ++d) a += bpp[d] * Wso[d * DS + c];
                red[t] = a;
            }
            __syncthreads();
            if (t < DS) ws[BSC + t] = bso[t] + red[t] + red[t + 128] + red[t + 256] + red[t + 384];
        }
    } else {
        // ---- sub side: 128 rows, 16 per wave, FULLY UNROLLED (exact R6) ----
        const int b2 = b - NBP;
        if (t < DS) {
            const float4* row = (const float4*)(Wsp + t * DI);
            float s = 0.f;
            #pragma unroll
            for (int d = 0; d < DI / 4; ++d) { float4 v = row[d]; s += v.x + v.y + v.z + v.w; }
            wcol[t] = s;
        }
        __syncthreads();
        const float2 wp = *(const float2*)(wcol + lane * 2);
        float2 acc = make_float2(0.f, 0.f);
        float z = 0.f;
        const int base = (b2 * 8 + wv) * 16;
        #pragma unroll
        for (int k = 0; k < 16; k += 2) {
            const int j0 = base + k, j1 = base + k + 1;
            const int g0 = sidx[j0], g1 = sidx[j1];
            const float2 x0 = *(const float2*)(sn + (size_t)g0 * DS + lane * 2);
            const float2 x1 = *(const float2*)(sn + (size_t)g1 * DS + lane * 2);
            float s0 = x0.x * wp.x + x0.y * wp.y;
            float s1 = x1.x * wp.x + x1.y * wp.y;
            #pragma unroll
            for (int m = 32; m >= 1; m >>= 1) {
                s0 += __shfl_xor(s0, m, 64);
                s1 += __shfl_xor(s1, m, 64);
            }
            const float e0 = __expf(s0), e1 = __expf(s1);
            const float2 y0 = *(const float2*)(sn + (size_t)j0 * DS + lane * 2);
            const float2 y1 = *(const float2*)(sn + (size_t)j1 * DS + lane * 2);
            acc.x += e0 * y0.x + e1 * y1.x;
            acc.y += e0 * y0.y + e1 * y1.y;
            z += e0 + e1;
        }
        ((float2*)(racc + wv * DS))[lane] = acc;
        if (lane == 0) rz[wv] = z;
        __syncthreads();
        if (t < DS) {
            float s = 0.f;
            #pragma unroll
            for (int w = 0; w < 8; ++w) s += racc[w * DS + t];
            acc2[t] = s;
        }
        if (t == 0) {
            float s = 0.f;
            #pragma unroll
            for (int w = 0; w < 8; ++w) s += rz[w];
            ws[ZS_OFF + b2] = s;
        }
        __syncthreads();
        // stage A: q[d] = sum_c acc2[c]*Wsp[c][d]
        {
            const int d = t & 127, g = t >> 7;
            float a = 0.f;
            #pragma unroll 8
            for (int c = g * 32; c < g * 32 + 32; ++c) a += acc2[c] * Wsp[c * DI + d];
            red[t] = a;
        }
        __syncthreads();
        if (t < DI) qv[t] = red[t] + red[t + 128] + red[t + 256] + red[t + 384];
        __syncthreads();
        // stage B: r[c] = sum_d qv[d]*Wpo[d][c]
        {
            const int c = t & 255, g = t >> 8;
            float a = 0.f;
            #pragma unroll 8
            for (int d = g * 64; d < g * 64 + 64; ++d) a += qv[d] * Wpo[d * DP + c];
            red[t] = a;
        }
        __syncthreads();
        if (t < DP) ws[RS_OFF + b2 * DP + t] = red[t] + red[t + 256];
        if (b2 == 0) {  // BPC = bpo + Wpo^T bsp
            __syncthreads();
            {
                const int c = t & 255, g = t >> 8;
                float a = 0.f;
                #pragma unroll 8
                for (int d = g * 64; d < g * 64 + 64; ++d) a += bsp[d] * Wpo[d * DP + c];
                red[t] = a;
            }
            __syncthreads();
            if (t < DP) ws[BPC + t] = bpo[t] + red[t] + red[t + 256];
        }
    }
}

// ---- k2: combine first (small L2 reads), then stream ----
__global__ __launch_bounds__(512)
void k2(const float* __restrict__ pn, const float* __restrict__ sn,
        const int* __restrict__ pidx, const int* __restrict__ sidx,
        const float* __restrict__ ws, float* __restrict__ out) {
    __shared__ float up[DP];
    __shared__ float us[DS];
    __shared__ float red[512];
    __shared__ float zsh[2];
    const int t = threadIdx.x;
    const int lane = t & 63;
    const int wv = t >> 6;
    const int b = blockIdx.x;
    const int start4 = b * CH4;
    const int end4 = start4 + CH4;

    if (wv == 0) {
        float z = ws[ZP_OFF + lane] + ws[ZP_OFF + 64 + lane]
                + ws[ZP_OFF + 128 + lane] + ws[ZP_OFF + 192 + lane];
        #pragma unroll
        for (int m = 32; m >= 1; m >>= 1) z += __shfl_xor(z, m, 64);
        if (lane == 0) zsh[0] = z;
    } else if (wv == 1) {
        float z = ws[ZS_OFF + lane];
        #pragma unroll
        for (int m = 32; m >= 1; m >>= 1) z += __shfl_xor(z, m, 64);
        if (lane == 0) zsh[1] = z;
    }
    __syncthreads();
    const float invZp = 1.f / zsh[0];
    const float invZs = 1.f / zsh[1];

    const bool needP = start4 < (O1 / 4);
    const bool needS = (end4 > (O2 / 4)) && (start4 < (O3 / 4));

    if (needP) {   // u_p = BPC + invZs * sum_b2 RS[b2][:]  (64 partials of 256)
        {
            const int c = t & 255, g = t >> 8;     // 2 groups of 32 blocks
            float a = 0.f;
            #pragma unroll 8
            for (int b2 = g * 32; b2 < g * 32 + 32; ++b2) a += ws[RS_OFF + b2 * DP + c];
            red[t] = a;
        }
        __syncthreads();
        if (t < DP) up[t] = ws[BPC + t] + invZs * (red[t] + red[t + 256]);
        __syncthreads();
    }
    if (needS) {   // u_s = BSC + invZp * sum_b1 RP[b1][:]  (256 partials of 128)
        {
            const int c = t & 127, g = t >> 7;     // 4 groups of 64 blocks
            float a = 0.f;
            #pragma unroll 8
            for (int b1 = g * 64; b1 < g * 64 + 64; ++b1) a += ws[RP_OFF + b1 * DS + c];
            red[t] = a;
        }
        __syncthreads();
        if (t < DS) us[t] = ws[BSC + t] + invZp * (red[t] + red[t + 128] + red[t + 256] + red[t + 384]);
        __syncthreads();
    }

    for (int g4 = start4 + t; g4 < end4; g4 += 512) {
        const int e4 = g4 * 4;
        float4 o;
        if (e4 < O1) {
            float4 x = *(const float4*)(pn + e4);
            int c = e4 & (DP - 1);
            o = make_float4(x.x + up[c], x.y + up[c + 1], x.z + up[c + 2], x.w + up[c + 3]);
        } else if (e4 < O2) {
            int i = e4 - O1;
            int4 v = *(const int4*)(pidx + i);
            o = make_float4((float)v.x, (float)v.y, (float)v.z, (float)v.w);
        } else if (e4 < O3) {
            int i = e4 - O2;
            float4 x = *(const float4*)(sn + i);
            int c = i & (DS - 1);
            o = make_float4(x.x + us[c], x.y + us[c + 1], x.z + us[c + 2], x.w + us[c + 3]);
        } else {
            int i = e4 - O3;
            int4 v = *(const int4*)(sidx + i);
            o = make_float4((float)v.x, (float)v.y, (float)v.z, (float)v.w);
        }
        *(float4*)(out + e4) = o;
    }
}

extern "C" void kernel_launch(void* const* d_in, const int* in_sizes, int n_in,
                              void* d_out, int out_size, void* d_ws, size_t ws_size,
                              hipStream_t stream) {
    const float* pn  = (const float*)d_in[0];
    const float* sn  = (const float*)d_in[1];
    const float* Wpp = (const float*)d_in[2];
    const float* bpp = (const float*)d_in[3];
    const float* Wsp = (const float*)d_in[4];
    const float* bsp = (const float*)d_in[5];
    const float* Wpo = (const float*)d_in[6];
    const float* bpo = (const float*)d_in[7];
    const float* Wso = (const float*)d_in[8];
    const float* bso = (const float*)d_in[9];
    const int* pidx  = (const int*)d_in[10];
    const int* sidx  = (const int*)d_in[11];
    float* ws  = (float*)d_ws;
    float* out = (float*)d_out;

    hipLaunchKernelGGL(k1, dim3(G1), dim3(512), 0, stream,
                       pn, sn, Wpp, bpp, Wsp, bsp, Wpo, bpo, Wso, bso, pidx, sidx, ws);
    hipLaunchKernelGGL(k2, dim3(G2), dim3(512), 0, stream,
                       pn, sn, pidx, sidx, ws, out);
}